// Round 9
// baseline (8760.305 us; speedup 1.0000x reference)
//
#include <hip/hip_runtime.h>

// voltageNN: 2-layer LSTM (H=256, P=1, in=1), T=1000, B=16384, + MLP head.
// One wave per 2 batch elements; lane owns units u = lane + 64k (k=0..3) for
// both layers, as 2 packed pairs per layer per batch.
// Round-8 = round-7's forced v_pk_*_f32 rational math, but wave reductions
// back on the PROVEN builtin update_dpp tree (rounds 3-6). Round-7's in-place
// v_add_f32_dpp asm hit the GFX9 "VALU-write -> DPP-read needs 2 wait states"
// hazard (compiler can't see inside asm strings to insert s_nop) -> wrong
// results. v_pk_* VOP3P ops have no such hazard class.
// Trans budget: 2 rcp per unit-pair per step (16/iter).
//   sigma(z) = (0.5*Q + u*P)/Q, u=z/2 prescaled, P,Q = tanh-CF [5/4] in v=u^2
//   tanh(z)  = z*P(v)/Q(v), CF [7/6], v=z^2
//   c' = f*c + i*g and o*tanh(c')*wr assembled over common denominators,
//   one merged rcp per pair per stage. (Numerics identical to round 5, which
//   passed with absmax 0.0.)

#define T_LEN 1000
#define WAVES 4     // waves per block
#define BPW   2     // batch elements per wave

typedef float v2f __attribute__((ext_vector_type(2)));

static __device__ __forceinline__ float rcpr(float x) { return __builtin_amdgcn_rcpf(x); }
static __device__ __forceinline__ v2f splat2(float s) { v2f r; r.x = s; r.y = s; return r; }

// ---- forced packed-f32 ops (VOP3P; plain VALU, no DPP hazard) ----
#define PK_MUL(d, a, b)    asm("v_pk_mul_f32 %0, %1, %2"     : "=v"(d) : "v"(a), "v"(b))
#define PK_FMA(d, a, b, c) asm("v_pk_fma_f32 %0, %1, %2, %3" : "=v"(d) : "v"(a), "v"(b), "v"(c))

template<int CTRL>
static __device__ __forceinline__ float dpp0(float x) {
    return __int_as_float(__builtin_amdgcn_update_dpp(
        0, __float_as_int(x), CTRL, 0xf, 0xf, true));
}
// sum across 64 lanes; result valid in lane 63 (compiler handles DPP hazards)
static __device__ __forceinline__ float wave_sum63(float x) {
    x += dpp0<0x111>(x);   // row_shr:1
    x += dpp0<0x112>(x);   // row_shr:2
    x += dpp0<0x114>(x);   // row_shr:4
    x += dpp0<0x118>(x);   // row_shr:8
    x += dpp0<0x142>(x);   // row_bcast:15
    x += dpp0<0x143>(x);   // row_bcast:31
    return x;
}
static __device__ __forceinline__ float lane63(float x) {
    return __int_as_float(__builtin_amdgcn_readlane(__float_as_int(x), 63));
}
static __device__ __forceinline__ float rdlane(float x, int l) {
    return __int_as_float(__builtin_amdgcn_readlane(__float_as_int(x), l));
}

// ---- Pade coefficients (exact, from tanh continued fraction) ----
struct PadeK {
    v2f sp2, sp1, sq2, sq1;                 // sigma [5/4] on u=z/2
    v2f tp3, tp2, tp1, tq3, tq2, tq1;       // tanh [7/6]
    v2f half, one;
};
static __device__ __forceinline__ void load_k(PadeK& K) {
    K.sp2 = splat2(5.2910053e-04f);  // 1/1890
    K.sp1 = splat2(5.5555556e-02f);  // 1/18
    K.sq2 = splat2(1.5873017e-02f);  // 1/63
    K.sq1 = splat2(4.4444445e-01f);  // 4/9
    K.tp3 = splat2(7.3999408e-06f);  // 1/135135
    K.tp2 = splat2(2.7972028e-03f);  // 2/715
    K.tp1 = splat2(1.2820513e-01f);  // 5/39
    K.tq3 = splat2(2.0720021e-04f);  // 4/19305
    K.tq2 = splat2(2.3310023e-02f);  // 10/429
    K.tq1 = splat2(4.6153846e-01f);  // 6/13
    K.half = splat2(0.5f);
    K.one  = splat2(1.0f);
}

// sigma(2u) as rational N/Q (u = z/2 pre-scaled into weights). 7 pk.
static __device__ __forceinline__ void sig_rat(const PadeK& K, v2f u, v2f& N, v2f& Q) {
    v2f v, p, t;
    PK_MUL(v, u, u);
    PK_FMA(p, v, K.sp2, K.sp1);
    PK_FMA(p, p, v, K.half);
    PK_FMA(Q, v, K.sq2, K.sq1);
    PK_FMA(Q, Q, v, K.one);
    PK_MUL(t, u, p);
    PK_FMA(N, Q, K.half, t);
}
// tanh(z) as rational N/Q. 8 pk.
static __device__ __forceinline__ void tanh_rat(const PadeK& K, v2f z, v2f& N, v2f& Q) {
    v2f v, p;
    PK_MUL(v, z, z);
    PK_FMA(p, v, K.tp3, K.tp2);
    PK_FMA(p, p, v, K.tp1);
    PK_FMA(p, p, v, K.one);
    PK_FMA(Q, v, K.tq3, K.tq2);
    PK_FMA(Q, Q, v, K.tq1);
    PK_FMA(Q, Q, v, K.one);
    PK_MUL(N, z, p);
}

struct CellW {
    v2f wi[2], wf[2], wg[2], wo[2];   // input weights (sigma gates prescaled x0.5)
    v2f vi[2], vf[2], vg[2], vo[2];   // recurrent weights
    v2f bi[2], bf[2], bg[2], bo[2];   // biases (bih+bhh)
    v2f wr[2];                        // projection row
};

static __device__ __forceinline__ void load_w(CellW& W, int lane,
        const float* __restrict__ Wih, const float* __restrict__ Whh,
        const float* __restrict__ bih, const float* __restrict__ bhh,
        const float* __restrict__ Whr) {
#pragma unroll
    for (int p = 0; p < 2; ++p) {
        int ua = lane + 128 * p;
        int ub = ua + 64;
        v2f t;
        t.x = Wih[ua];        t.y = Wih[ub];        W.wi[p] = t * 0.5f;
        t.x = Wih[256 + ua];  t.y = Wih[256 + ub];  W.wf[p] = t * 0.5f;
        t.x = Wih[512 + ua];  t.y = Wih[512 + ub];  W.wg[p] = t;
        t.x = Wih[768 + ua];  t.y = Wih[768 + ub];  W.wo[p] = t * 0.5f;
        t.x = Whh[ua];        t.y = Whh[ub];        W.vi[p] = t * 0.5f;
        t.x = Whh[256 + ua];  t.y = Whh[256 + ub];  W.vf[p] = t * 0.5f;
        t.x = Whh[512 + ua];  t.y = Whh[512 + ub];  W.vg[p] = t;
        t.x = Whh[768 + ua];  t.y = Whh[768 + ub];  W.vo[p] = t * 0.5f;
        t.x = bih[ua] + bhh[ua];
        t.y = bih[ub] + bhh[ub];                    W.bi[p] = t * 0.5f;
        t.x = bih[256 + ua] + bhh[256 + ua];
        t.y = bih[256 + ub] + bhh[256 + ub];        W.bf[p] = t * 0.5f;
        t.x = bih[512 + ua] + bhh[512 + ua];
        t.y = bih[512 + ub] + bhh[512 + ub];        W.bg[p] = t;
        t.x = bih[768 + ua] + bhh[768 + ua];
        t.y = bih[768 + ub] + bhh[768 + ub];        W.bo[p] = t * 0.5f;
        t.x = Whr[ua];        t.y = Whr[ub];        W.wr[p] = t;
    }
}

// One LSTM cell step for this lane's 4 units (2 packed pairs).
// xs, hs are pre-broadcast v2f. ~54 pk + ~7 scalar + 2 rcp per pair.
static __device__ __forceinline__ float cell(const CellW& W, const PadeK& K,
                                             v2f xs, v2f hs, v2f (&c)[2]) {
    float s = 0.0f;
#pragma unroll
    for (int p = 0; p < 2; ++p) {
        v2f ui, uf, uo, zg;
        PK_FMA(ui, hs, W.vi[p], W.bi[p]);  PK_FMA(ui, xs, W.wi[p], ui);
        PK_FMA(uf, hs, W.vf[p], W.bf[p]);  PK_FMA(uf, xs, W.wf[p], uf);
        PK_FMA(uo, hs, W.vo[p], W.bo[p]);  PK_FMA(uo, xs, W.wo[p], uo);
        PK_FMA(zg, hs, W.vg[p], W.bg[p]);  PK_FMA(zg, xs, W.wg[p], zg);

        v2f Ni, Qi, Nf, Qf, No, Qo, Ng, Qg;
        sig_rat(K, ui, Ni, Qi);
        sig_rat(K, uf, Nf, Qf);
        sig_rat(K, uo, No, Qo);
        tanh_rat(K, zg, Ng, Qg);

        // cn = (Ni*Ng*Qf + Nf*c*Qi*Qg) / (Qi*Qg*Qf): one merged rcp per pair
        v2f A, t1, t2, t3, NUM, DEN;
        PK_MUL(A, Qi, Qg);
        PK_MUL(t1, Ni, Ng);
        PK_MUL(t2, Nf, c[p]);
        PK_MUL(t3, t2, A);
        PK_FMA(NUM, t1, Qf, t3);
        PK_MUL(DEN, A, Qf);
        float rP = rcpr(DEN.x * DEN.y);
        v2f cn;
        cn.x = (NUM.x * DEN.y) * rP;
        cn.y = (NUM.y * DEN.x) * rP;
        c[p] = cn;

        // s += o * tanh(cn) * wr : one merged rcp per pair
        v2f Nt, Qt, t4, qq, D2;
        tanh_rat(K, cn, Nt, Qt);
        PK_MUL(t4, Nt, No);
        PK_MUL(qq, t4, W.wr[p]);
        PK_MUL(D2, Qo, Qt);
        float rQ = rcpr(D2.x * D2.y);
        float t5 = qq.x * D2.y;
        t5 = fmaf(qq.y, D2.x, t5);
        s = fmaf(t5, rQ, s);
    }
    return s;
}

__global__ __launch_bounds__(256, 1)
void voltage_lstm_kernel(const float* __restrict__ x,
        const float* __restrict__ Wih0, const float* __restrict__ Whh0,
        const float* __restrict__ bih0, const float* __restrict__ bhh0,
        const float* __restrict__ Whr0,
        const float* __restrict__ Wih1, const float* __restrict__ Whh1,
        const float* __restrict__ bih1, const float* __restrict__ bhh1,
        const float* __restrict__ Whr1,
        const float* __restrict__ W1, const float* __restrict__ b1p,
        const float* __restrict__ W2, const float* __restrict__ b2,
        float* __restrict__ out)
{
    __shared__ __align__(16) float h1buf[WAVES][BPW][T_LEN];

    const int lane = threadIdx.x & 63;
    const int wv   = threadIdx.x >> 6;
    const int w    = blockIdx.x * WAVES + wv;
    const int bA   = w * BPW;
    const int bB   = bA + 1;

    PadeK K;
    load_k(K);
    CellW W0c, W1c;
    load_w(W0c, lane, Wih0, Whh0, bih0, bhh0, Whr0);
    load_w(W1c, lane, Wih1, Whh1, bih1, bhh1, Whr1);

    v2f c0A[2], c0B[2], c1A[2], c1B[2];
#pragma unroll
    for (int p = 0; p < 2; ++p) {
        c0A[p] = splat2(0.f); c0B[p] = splat2(0.f);
        c1A[p] = splat2(0.f); c1B[p] = splat2(0.f);
    }

    const float* xA = x + (long)bA * T_LEN;
    const float* xB = x + (long)bB * T_LEN;
    float xcA = xA[lane];              // x chunk for t in [0,64)
    float xcB = xB[lane];

    // --- prologue: layer0 step 0 (h0=0) ---
    float h0A, h0B, h1A = 0.0f, h1B = 0.0f;
    {
        v2f z = splat2(0.0f);
        float sA = wave_sum63(cell(W0c, K, splat2(rdlane(xcA, 0)), z, c0A));
        float sB = wave_sum63(cell(W0c, K, splat2(rdlane(xcB, 0)), z, c0B));
        h0A = lane63(sA);
        h0B = lane63(sB);
    }

    // --- main loop: iter j computes layer0 step j+1 AND layer1 step j
    // (4 independent cell chains -> ILP).
    for (int j = 0; j < T_LEN - 1; ++j) {
        const int idx = j + 1;
        if ((idx & 63) == 0) {
            int tl = idx + lane;
            xcA = (tl < T_LEN) ? xA[tl] : 0.0f;
            xcB = (tl < T_LEN) ? xB[tl] : 0.0f;
        }
        v2f xtA = splat2(rdlane(xcA, idx & 63));
        v2f xtB = splat2(rdlane(xcB, idx & 63));
        v2f h0Av = splat2(h0A), h0Bv = splat2(h0B);
        v2f h1Av = splat2(h1A), h1Bv = splat2(h1B);

        float a0A = cell(W0c, K, xtA,  h0Av, c0A);
        float a0B = cell(W0c, K, xtB,  h0Bv, c0B);
        float a1A = cell(W1c, K, h0Av, h1Av, c1A);
        float a1B = cell(W1c, K, h0Bv, h1Bv, c1B);

        a0A = wave_sum63(a0A);
        a0B = wave_sum63(a0B);
        a1A = wave_sum63(a1A);
        a1B = wave_sum63(a1B);

        if (lane == 63) {
            h1buf[wv][0][j] = a1A;
            h1buf[wv][1][j] = a1B;
        }
        h0A = lane63(a0A);  h0B = lane63(a0B);
        h1A = lane63(a1A);  h1B = lane63(a1B);
    }
    // --- epilogue: layer1 step T-1 ---
    {
        float a1A = wave_sum63(cell(W1c, K, splat2(h0A), splat2(h1A), c1A));
        float a1B = wave_sum63(cell(W1c, K, splat2(h0B), splat2(h1B), c1B));
        if (lane == 63) {
            h1buf[wv][0][T_LEN - 1] = a1A;
            h1buf[wv][1][T_LEN - 1] = a1B;
        }
    }
    __syncthreads();

    // --- head: relu(h1 @ W1^T + b1) @ W2^T + b2 for both batches ---
    const float* hA = h1buf[wv][0];
    const float* hB = h1buf[wv][1];
    const int j0 = lane;                 // rows 0..63
    const int j1 = lane + 64;            // rows 64..99 (lanes 0..35)
    const bool has1 = (j1 < 100);
    const float* r0 = W1 + j0 * T_LEN;
    const float* r1 = W1 + (has1 ? j1 : 0) * T_LEN;
    float aA0 = 0.f, aA1 = 0.f, aB0 = 0.f, aB1 = 0.f;
    for (int t = 0; t < T_LEN; t += 4) {
        float4 u0 = *(const float4*)(r0 + t);
        float4 u1 = *(const float4*)(r1 + t);
        float4 pA = *(const float4*)(hA + t);
        float4 pB = *(const float4*)(hB + t);
        aA0 = fmaf(u0.x, pA.x, aA0); aA0 = fmaf(u0.y, pA.y, aA0);
        aA0 = fmaf(u0.z, pA.z, aA0); aA0 = fmaf(u0.w, pA.w, aA0);
        aA1 = fmaf(u1.x, pA.x, aA1); aA1 = fmaf(u1.y, pA.y, aA1);
        aA1 = fmaf(u1.z, pA.z, aA1); aA1 = fmaf(u1.w, pA.w, aA1);
        aB0 = fmaf(u0.x, pB.x, aB0); aB0 = fmaf(u0.y, pB.y, aB0);
        aB0 = fmaf(u0.z, pB.z, aB0); aB0 = fmaf(u0.w, pB.w, aB0);
        aB1 = fmaf(u1.x, pB.x, aB1); aB1 = fmaf(u1.y, pB.y, aB1);
        aB1 = fmaf(u1.z, pB.z, aB1); aB1 = fmaf(u1.w, pB.w, aB1);
    }
    float bb0 = b1p[j0],   w20 = W2[j0];
    float bb1 = has1 ? b1p[j1] : 0.f;
    float w21 = has1 ? W2[j1]  : 0.f;
    float sA = fmaxf(aA0 + bb0, 0.f) * w20;
    float sB = fmaxf(aB0 + bb0, 0.f) * w20;
    if (has1) {
        sA = fmaf(fmaxf(aA1 + bb1, 0.f), w21, sA);
        sB = fmaf(fmaxf(aB1 + bb1, 0.f), w21, sB);
    }
    sA = wave_sum63(sA);
    sB = wave_sum63(sB);
    if (lane == 63) {
        float bias2 = b2[0];
        out[bA] = sA + bias2;
        out[bB] = sB + bias2;
    }
}

extern "C" void kernel_launch(void* const* d_in, const int* in_sizes, int n_in,
                              void* d_out, int out_size, void* d_ws, size_t ws_size,
                              hipStream_t stream) {
    (void)in_sizes; (void)n_in; (void)d_ws; (void)ws_size; (void)out_size;
    const float* x    = (const float*)d_in[0];
    const float* Wih0 = (const float*)d_in[1];
    const float* Whh0 = (const float*)d_in[2];
    const float* bih0 = (const float*)d_in[3];
    const float* bhh0 = (const float*)d_in[4];
    const float* Whr0 = (const float*)d_in[5];
    const float* Wih1 = (const float*)d_in[6];
    const float* Whh1 = (const float*)d_in[7];
    const float* bih1 = (const float*)d_in[8];
    const float* bhh1 = (const float*)d_in[9];
    const float* Whr1 = (const float*)d_in[10];
    const float* W1   = (const float*)d_in[11];
    const float* b1   = (const float*)d_in[12];
    const float* W2   = (const float*)d_in[13];
    const float* b2   = (const float*)d_in[14];
    float* outp = (float*)d_out;

    dim3 grid(16384 / (WAVES * BPW)), block(256);
    voltage_lstm_kernel<<<grid, block, 0, stream>>>(
        x, Wih0, Whh0, bih0, bhh0, Whr0,
        Wih1, Whh1, bih1, bhh1, Whr1,
        W1, b1, W2, b2, outp);
}

// Round 10
// 8276.528 us; speedup vs baseline: 1.0585x; 1.0585x over previous
//
#include <hip/hip_runtime.h>

// voltageNN: 2-layer LSTM (H=256, P=1, in=1), T=1000, B=16384, + MLP head.
// Round-9: R6's exp2+merged-rcp math (best measured: 6.4ms) with BPW 2->4,
// WAVES 4->2 (same 32KB LDS/block, same 2048-block grid). 8 independent cell
// chains per wave to hide trans latency / amortize reduction+loop overhead.
// Lessons baked in: no pk asm (pk f32 is half-rate on gfx950 -> no gain),
// no Pade (2x FLOPs of exp2 form), no DPP asm (hazard nops needed), builtin
// update_dpp tree for reductions (compiler inserts hazards).
// Math per pair (2 units): 10 exp2 + 2 merged rcp:
//   sigma(z)=1/(1+I), I=2^(-L2E z); tanh(z)=(G-1)/(G+1), G=2^(2 L2E z)
//   cn = [u*c + (G-1)(1+F)] / [(1+F)*u],  u=(G+1)(1+I)
//   o*tanh(cn) = (E-1) / [(E+1)(1+O)],    E=2^(2 L2E cn)  (|c|<=~4.4, safe)

#define T_LEN 1000
#define WAVES 2     // waves per block
#define BPW   4     // batch elements per wave
#define L2E 1.44269504088896340736f

typedef float v2f __attribute__((ext_vector_type(2)));

static __device__ __forceinline__ float exp2r(float x) { return __builtin_amdgcn_exp2f(x); }
static __device__ __forceinline__ float rcpr (float x) { return __builtin_amdgcn_rcpf(x); }
static __device__ __forceinline__ v2f fma2(v2f a, v2f b, v2f c) {
    return __builtin_elementwise_fma(a, b, c);
}
static __device__ __forceinline__ v2f splat2(float s) { v2f r; r.x = s; r.y = s; return r; }
static __device__ __forceinline__ v2f swap2(v2f a) { return __builtin_shufflevector(a, a, 1, 0); }

template<int CTRL>
static __device__ __forceinline__ float dpp0(float x) {
    return __int_as_float(__builtin_amdgcn_update_dpp(
        0, __float_as_int(x), CTRL, 0xf, 0xf, true));
}
// sum across 64 lanes; result valid in lane 63
static __device__ __forceinline__ float wave_sum63(float x) {
    x += dpp0<0x111>(x);   // row_shr:1
    x += dpp0<0x112>(x);   // row_shr:2
    x += dpp0<0x114>(x);   // row_shr:4
    x += dpp0<0x118>(x);   // row_shr:8
    x += dpp0<0x142>(x);   // row_bcast:15
    x += dpp0<0x143>(x);   // row_bcast:31
    return x;
}
static __device__ __forceinline__ float lane63(float x) {
    return __int_as_float(__builtin_amdgcn_readlane(__float_as_int(x), 63));
}
static __device__ __forceinline__ float rdlane(float x, int l) {
    return __int_as_float(__builtin_amdgcn_readlane(__float_as_int(x), l));
}

struct CellW {
    v2f wi[2], wf[2], wg[2], wo[2];   // input weights (prescaled)
    v2f vi[2], vf[2], vg[2], vo[2];   // recurrent weights (prescaled)
    v2f bi[2], bf[2], bg[2], bo[2];   // biases (bih+bhh, prescaled)
    v2f wr[2];                        // projection row
};

static __device__ __forceinline__ void load_w(CellW& W, int lane,
        const float* __restrict__ Wih, const float* __restrict__ Whh,
        const float* __restrict__ bih, const float* __restrict__ bhh,
        const float* __restrict__ Whr) {
#pragma unroll
    for (int p = 0; p < 2; ++p) {
        int ua = lane + 128 * p;
        int ub = ua + 64;
        v2f t;
        t.x = Wih[ua];        t.y = Wih[ub];        W.wi[p] = t * (-L2E);
        t.x = Wih[256 + ua];  t.y = Wih[256 + ub];  W.wf[p] = t * (-L2E);
        t.x = Wih[512 + ua];  t.y = Wih[512 + ub];  W.wg[p] = t * (2.0f * L2E);
        t.x = Wih[768 + ua];  t.y = Wih[768 + ub];  W.wo[p] = t * (-L2E);
        t.x = Whh[ua];        t.y = Whh[ub];        W.vi[p] = t * (-L2E);
        t.x = Whh[256 + ua];  t.y = Whh[256 + ub];  W.vf[p] = t * (-L2E);
        t.x = Whh[512 + ua];  t.y = Whh[512 + ub];  W.vg[p] = t * (2.0f * L2E);
        t.x = Whh[768 + ua];  t.y = Whh[768 + ub];  W.vo[p] = t * (-L2E);
        t.x = bih[ua] + bhh[ua];
        t.y = bih[ub] + bhh[ub];                    W.bi[p] = t * (-L2E);
        t.x = bih[256 + ua] + bhh[256 + ua];
        t.y = bih[256 + ub] + bhh[256 + ub];        W.bf[p] = t * (-L2E);
        t.x = bih[512 + ua] + bhh[512 + ua];
        t.y = bih[512 + ub] + bhh[512 + ub];        W.bg[p] = t * (2.0f * L2E);
        t.x = bih[768 + ua] + bhh[768 + ua];
        t.y = bih[768 + ub] + bhh[768 + ub];        W.bo[p] = t * (-L2E);
        t.x = Whr[ua];        t.y = Whr[ub];        W.wr[p] = t;
    }
}

// One LSTM cell step for this lane's 4 units (2 packed pairs). x,h wave-uniform.
static __device__ __forceinline__ float cell(const CellW& W, float x, float h,
                                             v2f (&c)[2]) {
    float s = 0.0f;
    const v2f xs = splat2(x);
    const v2f hs = splat2(h);
#pragma unroll
    for (int p = 0; p < 2; ++p) {
        v2f yi = fma2(xs, W.wi[p], fma2(hs, W.vi[p], W.bi[p]));
        v2f yf = fma2(xs, W.wf[p], fma2(hs, W.vf[p], W.bf[p]));
        v2f yg = fma2(xs, W.wg[p], fma2(hs, W.vg[p], W.bg[p]));
        v2f yo = fma2(xs, W.wo[p], fma2(hs, W.vo[p], W.bo[p]));
        v2f I, F, G, O;
        I.x = exp2r(yi.x); I.y = exp2r(yi.y);
        F.x = exp2r(yf.x); F.y = exp2r(yf.y);
        G.x = exp2r(yg.x); G.y = exp2r(yg.y);
        O.x = exp2r(yo.x); O.y = exp2r(yo.y);
        v2f w1  = F + 1.0f;
        v2f u   = (G + 1.0f) * (I + 1.0f);
        v2f num = fma2(u, c[p], (G - 1.0f) * w1);
        v2f D   = w1 * u;                          // per-unit denominator
        float rP = rcpr(D.x * D.y);                // merged rcp (pair)
        v2f cn  = (num * swap2(D)) * splat2(rP);
        c[p] = cn;
        v2f yE = cn * splat2(2.0f * L2E);          // |c|<=~4.4 -> no overflow
        v2f E;
        E.x = exp2r(yE.x);
        E.y = exp2r(yE.y);
        v2f d = (E + 1.0f) * (O + 1.0f);
        float rQ = rcpr(d.x * d.y);                // merged rcp (pair)
        v2f q = ((E - 1.0f) * W.wr[p]) * swap2(d);
        s = fmaf(q.x + q.y, rQ, s);
    }
    return s;
}

__global__ __launch_bounds__(64 * WAVES, 1)
void voltage_lstm_kernel(const float* __restrict__ x,
        const float* __restrict__ Wih0, const float* __restrict__ Whh0,
        const float* __restrict__ bih0, const float* __restrict__ bhh0,
        const float* __restrict__ Whr0,
        const float* __restrict__ Wih1, const float* __restrict__ Whh1,
        const float* __restrict__ bih1, const float* __restrict__ bhh1,
        const float* __restrict__ Whr1,
        const float* __restrict__ W1, const float* __restrict__ b1p,
        const float* __restrict__ W2, const float* __restrict__ b2,
        float* __restrict__ out)
{
    __shared__ __align__(16) float h1buf[WAVES][BPW][T_LEN];

    const int lane = threadIdx.x & 63;
    const int wv   = threadIdx.x >> 6;
    const int w    = blockIdx.x * WAVES + wv;
    const int bA   = w * BPW;

    CellW W0c, W1c;
    load_w(W0c, lane, Wih0, Whh0, bih0, bhh0, Whr0);
    load_w(W1c, lane, Wih1, Whh1, bih1, bhh1, Whr1);

    v2f c0[BPW][2], c1[BPW][2];
#pragma unroll
    for (int b = 0; b < BPW; ++b) {
#pragma unroll
        for (int p = 0; p < 2; ++p) {
            c0[b][p] = splat2(0.f);
            c1[b][p] = splat2(0.f);
        }
    }

    const float* xp[BPW];
    float xc[BPW];
#pragma unroll
    for (int b = 0; b < BPW; ++b) {
        xp[b] = x + (long)(bA + b) * T_LEN;
        xc[b] = xp[b][lane];           // x chunk for t in [0,64)
    }

    // --- prologue: layer0 step 0 (h0=0) ---
    float h0[BPW], h1[BPW];
#pragma unroll
    for (int b = 0; b < BPW; ++b) {
        float s0 = wave_sum63(cell(W0c, rdlane(xc[b], 0), 0.0f, c0[b]));
        h0[b] = lane63(s0);
        h1[b] = 0.0f;
    }

    // --- main loop: iter j computes layer0 step j+1 AND layer1 step j
    // (8 independent cell chains across 4 batches -> deep ILP).
    for (int j = 0; j < T_LEN - 1; ++j) {
        const int idx = j + 1;
        if ((idx & 63) == 0) {
            int tl = idx + lane;
#pragma unroll
            for (int b = 0; b < BPW; ++b)
                xc[b] = (tl < T_LEN) ? xp[b][tl] : 0.0f;
        }
        float a0[BPW], a1[BPW];
#pragma unroll
        for (int b = 0; b < BPW; ++b) {
            float xt = rdlane(xc[b], idx & 63);
            a0[b] = cell(W0c, xt,    h0[b], c0[b]);
            a1[b] = cell(W1c, h0[b], h1[b], c1[b]);
        }
#pragma unroll
        for (int b = 0; b < BPW; ++b) {
            a0[b] = wave_sum63(a0[b]);
            a1[b] = wave_sum63(a1[b]);
        }
        if (lane == 63) {
#pragma unroll
            for (int b = 0; b < BPW; ++b)
                h1buf[wv][b][j] = a1[b];
        }
#pragma unroll
        for (int b = 0; b < BPW; ++b) {
            h0[b] = lane63(a0[b]);
            h1[b] = lane63(a1[b]);
        }
    }
    // --- epilogue: layer1 step T-1 ---
    {
        float a1[BPW];
#pragma unroll
        for (int b = 0; b < BPW; ++b)
            a1[b] = wave_sum63(cell(W1c, h0[b], h1[b], c1[b]));
        if (lane == 63) {
#pragma unroll
            for (int b = 0; b < BPW; ++b)
                h1buf[wv][b][T_LEN - 1] = a1[b];
        }
    }
    __syncthreads();

    // --- head: relu(h1 @ W1^T + b1) @ W2^T + b2 for all BPW batches ---
    const int j0 = lane;                 // rows 0..63
    const int j1 = lane + 64;            // rows 64..99 (lanes 0..35)
    const bool has1 = (j1 < 100);
    const float* r0 = W1 + j0 * T_LEN;
    const float* r1 = W1 + (has1 ? j1 : 0) * T_LEN;
    float acc0[BPW], acc1[BPW];
#pragma unroll
    for (int b = 0; b < BPW; ++b) { acc0[b] = 0.f; acc1[b] = 0.f; }
    for (int t = 0; t < T_LEN; t += 4) {
        float4 u0 = *(const float4*)(r0 + t);
        float4 u1 = *(const float4*)(r1 + t);
#pragma unroll
        for (int b = 0; b < BPW; ++b) {
            float4 pv = *(const float4*)(&h1buf[wv][b][t]);
            acc0[b] = fmaf(u0.x, pv.x, acc0[b]); acc0[b] = fmaf(u0.y, pv.y, acc0[b]);
            acc0[b] = fmaf(u0.z, pv.z, acc0[b]); acc0[b] = fmaf(u0.w, pv.w, acc0[b]);
            acc1[b] = fmaf(u1.x, pv.x, acc1[b]); acc1[b] = fmaf(u1.y, pv.y, acc1[b]);
            acc1[b] = fmaf(u1.z, pv.z, acc1[b]); acc1[b] = fmaf(u1.w, pv.w, acc1[b]);
        }
    }
    float bb0 = b1p[j0],   w20 = W2[j0];
    float bb1 = has1 ? b1p[j1] : 0.f;
    float w21 = has1 ? W2[j1]  : 0.f;
    float sred[BPW];
#pragma unroll
    for (int b = 0; b < BPW; ++b) {
        float s = fmaxf(acc0[b] + bb0, 0.f) * w20;
        if (has1) s = fmaf(fmaxf(acc1[b] + bb1, 0.f), w21, s);
        sred[b] = wave_sum63(s);
    }
    if (lane == 63) {
        float bias2 = b2[0];
#pragma unroll
        for (int b = 0; b < BPW; ++b)
            out[bA + b] = sred[b] + bias2;
    }
}

extern "C" void kernel_launch(void* const* d_in, const int* in_sizes, int n_in,
                              void* d_out, int out_size, void* d_ws, size_t ws_size,
                              hipStream_t stream) {
    (void)in_sizes; (void)n_in; (void)d_ws; (void)ws_size; (void)out_size;
    const float* x    = (const float*)d_in[0];
    const float* Wih0 = (const float*)d_in[1];
    const float* Whh0 = (const float*)d_in[2];
    const float* bih0 = (const float*)d_in[3];
    const float* bhh0 = (const float*)d_in[4];
    const float* Whr0 = (const float*)d_in[5];
    const float* Wih1 = (const float*)d_in[6];
    const float* Whh1 = (const float*)d_in[7];
    const float* bih1 = (const float*)d_in[8];
    const float* bhh1 = (const float*)d_in[9];
    const float* Whr1 = (const float*)d_in[10];
    const float* W1   = (const float*)d_in[11];
    const float* b1   = (const float*)d_in[12];
    const float* W2   = (const float*)d_in[13];
    const float* b2   = (const float*)d_in[14];
    float* outp = (float*)d_out;

    dim3 grid(16384 / (WAVES * BPW)), block(64 * WAVES);
    voltage_lstm_kernel<<<grid, block, 0, stream>>>(
        x, Wih0, Whh0, bih0, bhh0, Whr0,
        Wih1, Whh1, bih1, bhh1, Whr1,
        W1, b1, W2, b2, outp);
}